// Round 2
// baseline (491.319 us; speedup 1.0000x reference)
//
#include <hip/hip_runtime.h>

constexpr int B  = 2;
constexpr int NH = 8;
constexpr int L  = 512;
constexpr int D  = 64;
constexpr float INV_TEMP = 0.125f;   // 1/sqrt(D) = 1/8

// One block per (b, i). 256 threads.
// Phase 1: scores sc[h][j] = qs[h] . (adj_k[b,i,j,:] + ... ) wait: qs.k + qs.adj_k
//          = sum_d qs[h][d]*(k[b,h,j,d] + adj_k[b,i,j,d])  (q factored; k h-dep, adj not)
// Phase 2: mask + softmax per (h) row, write attn (global) + p (LDS).
// Phase 3: out[h][d] = sum_j p[h][j]*(v[b,h,j,d] + adj_v[b,i,j,d]).
__global__ __launch_bounds__(256, 4) void fused_attn(
    const float* __restrict__ q, const float* __restrict__ k,
    const float* __restrict__ v, const float* __restrict__ adj_k,
    const float* __restrict__ adj_v, const int* __restrict__ mask,
    float* __restrict__ out, float* __restrict__ attn) {
  const int b = blockIdx.x >> 9, i = blockIdx.x & (L - 1);
  const int t = threadIdx.x;
  __shared__ float qs[NH][D];    // 2 KB
  __shared__ float sc[NH][L];    // 16 KB

  // stage q (scaled by 1/8)
  for (int n = t; n < NH * D; n += 256) {
    int h = n >> 6, d = n & 63;
    qs[h][d] = q[(((size_t)b * NH + h) * L + i) * D + d] * INV_TEMP;
  }
  __syncthreads();

  // ---------------- phase 1: scores (each thread owns j1=t, j2=t+256) -------
  const float* akb = adj_k + ((size_t)b * L + i) * (size_t)L * D;
  const float* kb  = k + (size_t)b * NH * L * D;
  const int j1 = t, j2 = t + 256;
  float acc1[NH] = {}, acc2[NH] = {};
#pragma unroll
  for (int dc = 0; dc < D; dc += 16) {
    // adj_k rows for this dc-chunk: each 64B line consumed fully right here
    float4 a1[4], a2[4];
#pragma unroll
    for (int u = 0; u < 4; ++u) {
      a1[u] = *(const float4*)(akb + (size_t)j1 * D + dc + 4 * u);
      a2[u] = *(const float4*)(akb + (size_t)j2 * D + dc + 4 * u);
    }
#pragma unroll
    for (int h = 0; h < NH; ++h) {
      const float* k1p = kb + ((size_t)h * L + j1) * D + dc;
      const float* k2p = kb + ((size_t)h * L + j2) * D + dc;
      float s1 = acc1[h], s2 = acc2[h];
#pragma unroll
      for (int u = 0; u < 4; ++u) {
        float4 qv = *(const float4*)&qs[h][dc + 4 * u];   // wave-uniform bcast
        float4 k1 = *(const float4*)(k1p + 4 * u);        // L2-resident (2MB)
        float4 k2 = *(const float4*)(k2p + 4 * u);
        s1 = fmaf(qv.x, a1[u].x + k1.x, s1);
        s1 = fmaf(qv.y, a1[u].y + k1.y, s1);
        s1 = fmaf(qv.z, a1[u].z + k1.z, s1);
        s1 = fmaf(qv.w, a1[u].w + k1.w, s1);
        s2 = fmaf(qv.x, a2[u].x + k2.x, s2);
        s2 = fmaf(qv.y, a2[u].y + k2.y, s2);
        s2 = fmaf(qv.z, a2[u].z + k2.z, s2);
        s2 = fmaf(qv.w, a2[u].w + k2.w, s2);
      }
      acc1[h] = s1; acc2[h] = s2;
    }
  }
#pragma unroll
  for (int h = 0; h < NH; ++h) {   // banks = t%32 → 2-way (free)
    sc[h][j1] = acc1[h];
    sc[h][j2] = acc2[h];
  }
  __syncthreads();

  // ---------------- phase 2: mask + softmax (32 lanes per head row) ---------
  {
    const int h = t >> 5, l = t & 31;
    const int* mrow = mask + b * L;
    float* arow = attn + (((size_t)b * NH + h) * L + i) * L;
    float vals[16];
    float mx = -3.4e38f;
#pragma unroll
    for (int m = 0; m < 16; ++m) {
      int jj = l + (m << 5);
      float vsc = sc[h][jj];
      vsc = (mrow[jj] == 0) ? -10000.0f : vsc;
      vals[m] = vsc;
      mx = fmaxf(mx, vsc);
    }
#pragma unroll
    for (int off = 16; off > 0; off >>= 1) mx = fmaxf(mx, __shfl_xor(mx, off, 32));
    float sum = 0.f;
#pragma unroll
    for (int m = 0; m < 16; ++m) { vals[m] = __expf(vals[m] - mx); sum += vals[m]; }
#pragma unroll
    for (int off = 16; off > 0; off >>= 1) sum += __shfl_xor(sum, off, 32);
    const float inv = 1.0f / sum;
    // each thread writes exactly the sc elements it read — no barrier needed
#pragma unroll
    for (int m = 0; m < 16; ++m) {
      int jj = l + (m << 5);
      float p = vals[m] * inv;
      arow[jj] = p;      // attn output, only HBM pass for attn
      sc[h][jj] = p;     // reuse for phase 3
    }
  }
  __syncthreads();

  // ---------------- phase 3: out = sum_j p * (v + adj_v) --------------------
  {
    const int d = t & 63, h0 = t >> 6;           // this thread: heads h0, h0+4
    const float* avb = adj_v + ((size_t)b * L + i) * (size_t)L * D + d;
    const float* vp0 = v + (((size_t)b * NH + h0) * L) * D + d;       // L2-res
    const float* vp1 = v + (((size_t)b * NH + h0 + 4) * L) * D + d;
    float o0a = 0.f, o0b = 0.f, o1a = 0.f, o1b = 0.f;
#pragma unroll 2
    for (int j = 0; j < L; j += 2) {
      float av0 = avb[(size_t)j * D];            // 256B coalesced per wave
      float av1 = avb[(size_t)(j + 1) * D];
      float p00 = sc[h0][j],     p01 = sc[h0][j + 1];      // uniform bcast
      float p10 = sc[h0 + 4][j], p11 = sc[h0 + 4][j + 1];
      o0a = fmaf(p00, av0 + vp0[(size_t)j * D], o0a);
      o0b = fmaf(p01, av1 + vp0[(size_t)(j + 1) * D], o0b);
      o1a = fmaf(p10, av0 + vp1[(size_t)j * D], o1a);
      o1b = fmaf(p11, av1 + vp1[(size_t)(j + 1) * D], o1b);
    }
    const size_t ob = (((size_t)b * NH + h0) * L + i) * D + d;
    out[ob] = o0a + o0b;
    out[ob + (size_t)4 * L * D] = o1a + o1b;
  }
}

// ---------------------------------------------------------------------------
extern "C" void kernel_launch(void* const* d_in, const int* in_sizes, int n_in,
                              void* d_out, int out_size, void* d_ws, size_t ws_size,
                              hipStream_t stream) {
  const float* q     = (const float*)d_in[0];
  const float* k     = (const float*)d_in[1];
  const float* v     = (const float*)d_in[2];
  const float* adj_k = (const float*)d_in[3];
  const float* adj_v = (const float*)d_in[4];
  const int*   mask  = (const int*)d_in[5];
  float* out  = (float*)d_out;
  float* attn = out + (size_t)B * NH * L * D;   // second output region

  fused_attn<<<B * L, 256, 0, stream>>>(q, k, v, adj_k, adj_v, mask, out, attn);
}

// Round 3
// 352.915 us; speedup vs baseline: 1.3922x; 1.3922x over previous
//
#include <hip/hip_runtime.h>

constexpr int B  = 2;
constexpr int NH = 8;
constexpr int L  = 512;
constexpr int D  = 64;
constexpr float INV_TEMP = 0.125f;   // 1/sqrt(D) = 1/8

// ---------------------------------------------------------------------------
// K1: S1[b,h,i,j] = (q[b,h,i,:]/8) . k[b,h,j,:]  -> d_ws
// grid (16, L/64, L/128), block 256. Tiles: 64 i x 128 j, K=64 staged once.
// Register tile 4x8 (cyclic i=i0+16m, j=j0+16n) so LDS b128 reads are
// 2-way/broadcast (free). Staging writes are 8-way but one-time (~1.4 us).
// ---------------------------------------------------------------------------
__global__ __launch_bounds__(256) void k1_qk(const float* __restrict__ q,
                                             const float* __restrict__ k,
                                             float* __restrict__ s1) {
  const int bh = blockIdx.x, it = blockIdx.y, jt = blockIdx.z;
  __shared__ float Qs[64][68];    // [i][d], stride 68: b128-aligned, 2-way banks
  __shared__ float Ks[128][68];   // [j][d]
  const int t = threadIdx.x;
  const float* qb = q + ((size_t)bh * L + it * 64) * D;
  const float* kb = k + ((size_t)bh * L + jt * 128) * D;
#pragma unroll
  for (int n0 = 0; n0 < 4; ++n0) {            // Q tile: 64x64 = 1024 float4
    int n = t + (n0 << 8);
    int r = n >> 4, c = (n & 15) << 2;
    float4 a = *(const float4*)(qb + (size_t)r * D + c);
    a.x *= INV_TEMP; a.y *= INV_TEMP; a.z *= INV_TEMP; a.w *= INV_TEMP;
    *(float4*)&Qs[r][c] = a;
  }
#pragma unroll
  for (int n0 = 0; n0 < 8; ++n0) {            // K tile: 128x64 = 2048 float4
    int n = t + (n0 << 8);
    int r = n >> 4, c = (n & 15) << 2;
    *(float4*)&Ks[r][c] = *(const float4*)(kb + (size_t)r * D + c);
  }
  __syncthreads();
  const int i0 = t >> 4, j0 = t & 15;         // i = i0+16m (m<4), j = j0+16n (n<8)
  float acc[4][8] = {};
#pragma unroll 1
  for (int kc = 0; kc < 64; kc += 4) {
    float4 a[4], b[8];
#pragma unroll
    for (int m = 0; m < 4; ++m) a[m] = *(const float4*)&Qs[i0 + 16 * m][kc];
#pragma unroll
    for (int n = 0; n < 8; ++n) b[n] = *(const float4*)&Ks[j0 + 16 * n][kc];
#pragma unroll
    for (int m = 0; m < 4; ++m)
#pragma unroll
      for (int n = 0; n < 8; ++n)
        acc[m][n] = fmaf(a[m].x, b[n].x,
                    fmaf(a[m].y, b[n].y,
                    fmaf(a[m].z, b[n].z,
                    fmaf(a[m].w, b[n].w, acc[m][n]))));
  }
  float* sb = s1 + ((size_t)bh * L + it * 64) * L + jt * 128;
#pragma unroll
  for (int m = 0; m < 4; ++m) {
    float* srow = sb + (size_t)(i0 + 16 * m) * L;
#pragma unroll
    for (int n = 0; n < 8; ++n) srow[j0 + 16 * n] = acc[m][n];
  }
}

// ---------------------------------------------------------------------------
// K2: one block per (b,i).
//  A: scores sc[h][j] = S1 + q/8 . adj_k  (adj_k staged in LDS, coalesced)
//  B: mask + softmax -> attn (global) + p (LDS)
//  C: out[h][d] = sum_j p * (v + adj_v)   (lane = d: fully coalesced streams;
//     p broadcast via v_readlane from registers - no LDS in inner loop)
// ---------------------------------------------------------------------------
__global__ __launch_bounds__(256) void k2_fused(
    const float* __restrict__ q, const float* __restrict__ k,
    const float* __restrict__ v, const float* __restrict__ adj_k,
    const float* __restrict__ adj_v, const int* __restrict__ mask,
    const float* __restrict__ s1, float* __restrict__ out,
    float* __restrict__ attn) {
  const int b = blockIdx.x >> 9, i = blockIdx.x & (L - 1);
  const int t = threadIdx.x;
  const int lane = t & 63;
  const int hp = __builtin_amdgcn_readfirstlane(t >> 6);  // wave-uniform: heads hp, hp+4
  __shared__ float sc[NH][L];     // 16 KB
  __shared__ float ak[64][65];    // 16.6 KB, +1 pad: all b32 access 2-way max

  const float* akb  = adj_k + ((size_t)b * L + i) * (size_t)L * D;
  const float* qr0  = q + (((size_t)b * NH + hp    ) * L + i) * D;  // uniform -> s_load
  const float* qr1  = q + (((size_t)b * NH + hp + 4) * L + i) * D;
  const float* s1r0 = s1 + (((size_t)b * NH + hp    ) * L + i) * L;
  const float* s1r1 = s1 + (((size_t)b * NH + hp + 4) * L + i) * L;

  // ---------------- phase A: scores ----------------------------------------
  for (int jc = 0; jc < L; jc += 64) {
    __syncthreads();                          // protect ak reuse
#pragma unroll
    for (int n0 = 0; n0 < 4; ++n0) {          // stage 64 rows x 64 d, coalesced
      int n = t + (n0 << 8);
      int r = n >> 4, c = (n & 15) << 2;
      float4 a = *(const float4*)(akb + (size_t)(jc + r) * D + c);
      ak[r][c] = a.x; ak[r][c + 1] = a.y; ak[r][c + 2] = a.z; ak[r][c + 3] = a.w;
    }
    __syncthreads();
    float acc0 = 0.f, acc1 = 0.f;             // this thread: j = jc+lane
#pragma unroll
    for (int dc = 0; dc < D; dc += 4) {
      float a0 = ak[lane][dc],     a1 = ak[lane][dc + 1];
      float a2 = ak[lane][dc + 2], a3 = ak[lane][dc + 3];
      float4 q0 = *(const float4*)(qr0 + dc); // wave-uniform (scalar path)
      float4 q1 = *(const float4*)(qr1 + dc);
      acc0 = fmaf(q0.x, a0, fmaf(q0.y, a1, fmaf(q0.z, a2, fmaf(q0.w, a3, acc0))));
      acc1 = fmaf(q1.x, a0, fmaf(q1.y, a1, fmaf(q1.z, a2, fmaf(q1.w, a3, acc1))));
    }
    sc[hp    ][jc + lane] = s1r0[jc + lane] + acc0 * INV_TEMP;
    sc[hp + 4][jc + lane] = s1r1[jc + lane] + acc1 * INV_TEMP;
  }
  __syncthreads();

  // ---------------- phase B: mask + softmax --------------------------------
  {
    const int h = t >> 5, l = t & 31;
    const int* mrow = mask + b * L;
    float* arow = attn + (((size_t)b * NH + h) * L + i) * L;
    float vals[16];
    float mx = -3.4e38f;
#pragma unroll
    for (int m = 0; m < 16; ++m) {
      int jj = l + (m << 5);
      float vsc = sc[h][jj];
      vsc = (mrow[jj] == 0) ? -10000.0f : vsc;
      vals[m] = vsc;
      mx = fmaxf(mx, vsc);
    }
#pragma unroll
    for (int off = 16; off > 0; off >>= 1) mx = fmaxf(mx, __shfl_xor(mx, off, 32));
    float sum = 0.f;
#pragma unroll
    for (int m = 0; m < 16; ++m) { vals[m] = __expf(vals[m] - mx); sum += vals[m]; }
#pragma unroll
    for (int off = 16; off > 0; off >>= 1) sum += __shfl_xor(sum, off, 32);
    const float inv = 1.0f / sum;
#pragma unroll
    for (int m = 0; m < 16; ++m) {
      int jj = l + (m << 5);
      float p = vals[m] * inv;
      arow[jj] = p;       // attn output (only HBM pass for attn)
      sc[h][jj] = p;      // reuse for phase C
    }
  }
  __syncthreads();

  // ---------------- phase C: out = sum_j p * (v + adj_v) -------------------
  {
    const float* avp = adj_v + ((size_t)b * L + i) * (size_t)L * D + lane;  // lane = d
    const float* v0p = v + ((size_t)b * NH + hp    ) * (size_t)L * D + lane;
    const float* v1p = v + ((size_t)b * NH + hp + 4) * (size_t)L * D + lane;
    float o0 = 0.f, o1 = 0.f;
    for (int jc = 0; jc < L; jc += 64) {
      float p0 = sc[hp    ][jc + lane];       // wave's p-chunk into lanes
      float p1 = sc[hp + 4][jc + lane];
      const float* ap = avp + (size_t)jc * D;
      const float* w0 = v0p + (size_t)jc * D;
      const float* w1 = v1p + (size_t)jc * D;
#pragma unroll 16
      for (int j = 0; j < 64; ++j) {          // j uniform -> v_readlane
        float pj0 = __uint_as_float(__builtin_amdgcn_readlane(__float_as_uint(p0), j));
        float pj1 = __uint_as_float(__builtin_amdgcn_readlane(__float_as_uint(p1), j));
        float av = ap[(size_t)j * D];         // 256B coalesced rows
        float w0v = w0[(size_t)j * D];
        float w1v = w1[(size_t)j * D];
        o0 = fmaf(pj0, av + w0v, o0);
        o1 = fmaf(pj1, av + w1v, o1);
      }
    }
    const size_t ob = (((size_t)b * NH + hp) * L + i) * D + lane;
    out[ob] = o0;
    out[ob + (size_t)4 * L * D] = o1;
  }
}

// ---------------------------------------------------------------------------
extern "C" void kernel_launch(void* const* d_in, const int* in_sizes, int n_in,
                              void* d_out, int out_size, void* d_ws, size_t ws_size,
                              hipStream_t stream) {
  const float* q     = (const float*)d_in[0];
  const float* k     = (const float*)d_in[1];
  const float* v     = (const float*)d_in[2];
  const float* adj_k = (const float*)d_in[3];
  const float* adj_v = (const float*)d_in[4];
  const int*   mask  = (const int*)d_in[5];
  float* out  = (float*)d_out;
  float* attn = out + (size_t)B * NH * L * D;   // second output region
  float* s1   = (float*)d_ws;                   // B*NH*L*L fp32 = 16.8 MB

  dim3 g1(B * NH, L / 64, L / 128);
  k1_qk<<<g1, 256, 0, stream>>>(q, k, s1);
  k2_fused<<<B * L, 256, 0, stream>>>(q, k, v, adj_k, adj_v, mask, s1, out, attn);
}